// Round 7
// baseline (1031.115 us; speedup 1.0000x reference)
//
#include <hip/hip_runtime.h>

#define HID 64
#define NPB 128    // nodes per bucket (bucket = dst >> 7)
#define CAP 2048   // per-bucket edge capacity: mean 1280, sd ~36 -> ~20 sigma margin
#define DFT 512    // block size (8 waves)
#define PADW 68    // acc row stride (fp32): 68*4=272B, 16B-aligned, bank-spreading

typedef __attribute__((ext_vector_type(8))) short bf16x8;
typedef __attribute__((ext_vector_type(4))) float f32x4;

__device__ inline float bf2f(unsigned short u) {
  return __uint_as_float((unsigned int)u << 16);
}
__device__ inline unsigned short f2bf(float f) {
  unsigned int u = __float_as_uint(f);
  u += 0x7fff + ((u >> 16) & 1);  // round-to-nearest-even
  return (unsigned short)(u >> 16);
}
__device__ inline float bfLo(unsigned int u) { return __uint_as_float(u << 16); }
__device__ inline float bfHi(unsigned int u) { return __uint_as_float(u & 0xffff0000u); }

// ---- S1: hist + reserve + scatter into fixed-capacity buckets, PLUS global
// float-atomic degree accumulation (deg[dst] += ew; deg memset to 0, self-loop
// +1 added in k_proj). Record: {src | dLoc<<24, ew}. ----
__global__ __launch_bounds__(DFT) void k_bucket1(const int* __restrict__ src,
                                                 const int* __restrict__ dst,
                                                 const float* __restrict__ ew,
                                                 unsigned int* __restrict__ bucketCnt,  // B*16 padded
                                                 int2* __restrict__ edges,
                                                 float* __restrict__ deg,
                                                 int B, int ept, int nE) {
  __shared__ unsigned int hist[1024];
  hist[threadIdx.x] = 0;
  hist[threadIdx.x + 512] = 0;
  __syncthreads();
  int base = blockIdx.x * DFT * ept;
  for (int i = 0; i < ept; ++i) {
    int e = base + i * DFT + threadIdx.x;
    if (e < nE) atomicAdd(&hist[(unsigned)dst[e] >> 7], 1u);
  }
  __syncthreads();
  for (int c = threadIdx.x; c < B; c += DFT) {
    unsigned int h = hist[c];
    unsigned int b = 0;
    if (h) b = atomicAdd(&bucketCnt[c * 16], h);  // 64B-padded line per bucket
    hist[c] = (unsigned)(c * CAP) + b;            // absolute write cursor
  }
  __syncthreads();
  for (int i = 0; i < ept; ++i) {
    int e = base + i * DFT + threadIdx.x;
    if (e < nE) {
      int d = dst[e];
      float w = ew[e];
      int c = (unsigned)d >> 7;
      int slot = (int)atomicAdd(&hist[c], 1u);
      if (slot < (c + 1) * CAP)  // never taken statistically; memory safety only
        edges[slot] = make_int2(src[e] | ((d & 127) << 24), __float_as_int(w));
      atomicAdd(&deg[d], w);  // global_atomic_add_f32
    }
  }
}

// ---- S2: dinv = rsqrt(1 + deg) + MFMA gemm1 over this bucket's 128 rows.
// P1 = bf16(dinv[row] * (X @ W1)) -> d_out first half (dead before final agg). ----
__global__ __launch_bounds__(DFT) void k_proj(const float* __restrict__ X,
                                              const float* __restrict__ W,
                                              const float* __restrict__ deg,
                                              float* __restrict__ dinv,
                                              unsigned short* __restrict__ Out, int n) {
  __shared__ float sdi[NPB];
  int c = blockIdx.x;
  int t = threadIdx.x;
  if (t < NPB) {
    int g = c * NPB + t;
    float di = 0.f;
    if (g < n) {
      di = rsqrtf(1.0f + deg[g]);
      dinv[g] = di;
    }
    sdi[t] = di;
  }
  __syncthreads();
  int wv = t >> 6;
  int lane = t & 63;
  int m16 = lane & 15;
  int q = lane >> 4;
  bf16x8 Bb[4][2], Br[4][2];
#pragma unroll
  for (int nt = 0; nt < 4; ++nt)
#pragma unroll
    for (int kh = 0; kh < 2; ++kh) {
      int ncol = nt * 16 + m16;
      int k0 = kh * 32 + q * 8;
#pragma unroll
      for (int j = 0; j < 8; ++j) {
        float w = W[(k0 + j) * HID + ncol];  // L1-hot (16 KB)
        unsigned short wb = f2bf(w);
        Bb[nt][kh][j] = (short)wb;
        Br[nt][kh][j] = (short)f2bf(w - bf2f(wb));
      }
    }
  int rowBase = c * NPB + wv * 16;  // 8 waves x 16 rows = 128
  if (rowBase >= n) return;
  int mc = rowBase + m16;
  if (mc >= n) mc = n - 1;  // clamped load; stores guarded
  bf16x8 A[2];
  const float* Xp = X + (size_t)mc * HID;
#pragma unroll
  for (int kh = 0; kh < 2; ++kh) {
    f32x4 x0 = *(const f32x4*)(Xp + kh * 32 + q * 8);
    f32x4 x1 = *(const f32x4*)(Xp + kh * 32 + q * 8 + 4);
#pragma unroll
    for (int j = 0; j < 4; ++j) {
      A[kh][j] = (short)f2bf(x0[j]);
      A[kh][4 + j] = (short)f2bf(x1[j]);
    }
  }
  float dv = sdi[wv * 16 + m16];
#pragma unroll
  for (int nt = 0; nt < 4; ++nt) {
    f32x4 acc = {0.f, 0.f, 0.f, 0.f};
    // swapped operands -> D transposed: lane holds row rowBase+m16,
    // cols nt*16 + q*4 + r  => one contiguous 8B bf16x4 store per nt
    acc = __builtin_amdgcn_mfma_f32_16x16x32_bf16(Bb[nt][0], A[0], acc, 0, 0, 0);
    acc = __builtin_amdgcn_mfma_f32_16x16x32_bf16(Bb[nt][1], A[1], acc, 0, 0, 0);
    acc = __builtin_amdgcn_mfma_f32_16x16x32_bf16(Br[nt][0], A[0], acc, 0, 0, 0);
    acc = __builtin_amdgcn_mfma_f32_16x16x32_bf16(Br[nt][1], A[1], acc, 0, 0, 0);
    if (rowBase + m16 < n) {
      ushort4 o;
      o.x = f2bf(acc[0] * dv);
      o.y = f2bf(acc[1] * dv);
      o.z = f2bf(acc[2] * dv);
      o.w = f2bf(acc[3] * dv);
      *(ushort4*)(&Out[(size_t)(rowBase + m16) * HID + nt * 16 + q * 4]) = o;
    }
  }
}

// Edge-centric streaming aggregate into LDS accumulator. Per 8-edge wave step:
// group q (8 lanes) owns edge idx0+q; all lanes of the group load the same 8B
// record (one 64B line per wave), gather the 128B src row (16B/lane), scale by
// norm = ew*dinv[dst], ds_add_f32 into acc[dLoc]. Zero divergence, exactly one
// gather per edge. Garbage tail records: norm=0, src clamped, dLoc masked.
#define AGG_STREAM(EDGES, I0, BC, H8P, ACC, SDI)                              \
  for (int idx0 = wv * 8; idx0 < (BC); idx0 += 64) {                          \
    int idx = idx0 + q;                                                       \
    bool ok = idx < (BC);                                                     \
    int2 r = (EDGES)[(I0) + idx];                                             \
    unsigned s = ok ? ((unsigned)r.x & 0xFFFFFFu) : 0u;                       \
    int dl = ((unsigned)r.x >> 24) & 127;                                     \
    float norm = ok ? __int_as_float(r.y) * (SDI)[dl] : 0.f;                  \
    uint4 h = (H8P)[(size_t)s * 8u + ql];                                     \
    float* a = &(ACC)[dl * PADW + ql * 8];                                    \
    atomicAdd(&a[0], norm * bfLo(h.x));                                       \
    atomicAdd(&a[1], norm * bfHi(h.x));                                       \
    atomicAdd(&a[2], norm * bfLo(h.y));                                       \
    atomicAdd(&a[3], norm * bfHi(h.y));                                       \
    atomicAdd(&a[4], norm * bfLo(h.z));                                       \
    atomicAdd(&a[5], norm * bfHi(h.z));                                       \
    atomicAdd(&a[6], norm * bfLo(h.w));                                       \
    atomicAdd(&a[7], norm * bfHi(h.w));                                       \
  }

// ---- S3: layer-1 aggregate (edge-centric) + fused layer-2 projection.
// acc init = dinv*ownP1 (self-loop), stream edges, then gemm2 reading
// A = bf16(relu(acc + b1)) from LDS; P2 = bf16(dinv*(h1@W2)). ----
__global__ __launch_bounds__(DFT) void k_aggL1(const int2* __restrict__ edges,
                                               const unsigned int* __restrict__ bucketCnt,
                                               const float* __restrict__ dinv,
                                               const uint4* __restrict__ H8,  // P1
                                               const float* __restrict__ b1,
                                               const float* __restrict__ W,   // W2
                                               unsigned short* __restrict__ Out,  // P2
                                               int n) {
  __shared__ float acc[NPB * PADW];  // 34.8 KB -> 4 blocks/CU
  __shared__ float sdi[NPB];
  int c = blockIdx.x;
  int t = threadIdx.x;
  int base = c * NPB;
  if (t < NPB) {
    int g = base + t;
    sdi[t] = (g < n) ? dinv[g] : 0.f;
  }
  __syncthreads();
  for (int k = t; k < NPB * 8; k += DFT) {  // init: 2 uint4 per thread
    int row = k >> 3, c8 = k & 7;
    int g = base + row;
    float di = sdi[row];
    uint4 v = (g < n) ? H8[(size_t)g * 8 + c8] : make_uint4(0, 0, 0, 0);
    float* a = &acc[row * PADW + c8 * 8];
    a[0] = di * bfLo(v.x); a[1] = di * bfHi(v.x);
    a[2] = di * bfLo(v.y); a[3] = di * bfHi(v.y);
    a[4] = di * bfLo(v.z); a[5] = di * bfHi(v.z);
    a[6] = di * bfLo(v.w); a[7] = di * bfHi(v.w);
  }
  __syncthreads();
  int bc = (int)bucketCnt[c * 16];
  if (bc > CAP) bc = CAP;
  int i0 = c * CAP;
  int wv = t >> 6;
  int lane = t & 63;
  int q = lane >> 3;
  int ql = lane & 7;
  AGG_STREAM(edges, i0, bc, H8, acc, sdi)
  __syncthreads();
  // ---- gemm2: 8 waves x 16-row slices; A = relu(acc+b1) from LDS ----
  int m16 = lane & 15;
  int qq = lane >> 4;
  bf16x8 Bb[4][2], Br[4][2];
#pragma unroll
  for (int nt = 0; nt < 4; ++nt)
#pragma unroll
    for (int kh = 0; kh < 2; ++kh) {
      int ncol = nt * 16 + m16;
      int k0 = kh * 32 + qq * 8;
#pragma unroll
      for (int j = 0; j < 8; ++j) {
        float w = W[(k0 + j) * HID + ncol];  // L1-hot
        unsigned short wb = f2bf(w);
        Bb[nt][kh][j] = (short)wb;
        Br[nt][kh][j] = (short)f2bf(w - bf2f(wb));
      }
    }
  int rowL = wv * 16 + m16;  // 0..127
  bf16x8 A[2];
#pragma unroll
  for (int kh = 0; kh < 2; ++kh) {
    int k0 = kh * 32 + qq * 8;
#pragma unroll
    for (int j = 0; j < 8; ++j) {
      float hv = fmaxf(acc[rowL * PADW + k0 + j] + b1[k0 + j], 0.f);
      A[kh][j] = (short)f2bf(hv);
    }
  }
  float dv = sdi[rowL];
  int g = base + rowL;
#pragma unroll
  for (int nt = 0; nt < 4; ++nt) {
    f32x4 o4 = {0.f, 0.f, 0.f, 0.f};
    o4 = __builtin_amdgcn_mfma_f32_16x16x32_bf16(Bb[nt][0], A[0], o4, 0, 0, 0);
    o4 = __builtin_amdgcn_mfma_f32_16x16x32_bf16(Bb[nt][1], A[1], o4, 0, 0, 0);
    o4 = __builtin_amdgcn_mfma_f32_16x16x32_bf16(Br[nt][0], A[0], o4, 0, 0, 0);
    o4 = __builtin_amdgcn_mfma_f32_16x16x32_bf16(Br[nt][1], A[1], o4, 0, 0, 0);
    if (g < n) {
      ushort4 o;
      o.x = f2bf(o4[0] * dv);
      o.y = f2bf(o4[1] * dv);
      o.z = f2bf(o4[2] * dv);
      o.w = f2bf(o4[3] * dv);
      *(ushort4*)(&Out[(size_t)g * HID + nt * 16 + qq * 4]) = o;
    }
  }
}

// ---- S4: layer-2 aggregate (edge-centric) + b2 -> fp32 output. ----
__global__ __launch_bounds__(DFT) void k_aggL2(const int2* __restrict__ edges,
                                               const unsigned int* __restrict__ bucketCnt,
                                               const float* __restrict__ dinv,
                                               const uint4* __restrict__ H8,  // P2
                                               const float* __restrict__ b2,
                                               float* __restrict__ out, int n) {
  __shared__ float acc[NPB * PADW];
  __shared__ float sdi[NPB];
  int c = blockIdx.x;
  int t = threadIdx.x;
  int base = c * NPB;
  if (t < NPB) {
    int g = base + t;
    sdi[t] = (g < n) ? dinv[g] : 0.f;
  }
  __syncthreads();
  for (int k = t; k < NPB * 8; k += DFT) {
    int row = k >> 3, c8 = k & 7;
    int g = base + row;
    float di = sdi[row];
    uint4 v = (g < n) ? H8[(size_t)g * 8 + c8] : make_uint4(0, 0, 0, 0);
    float* a = &acc[row * PADW + c8 * 8];
    a[0] = di * bfLo(v.x); a[1] = di * bfHi(v.x);
    a[2] = di * bfLo(v.y); a[3] = di * bfHi(v.y);
    a[4] = di * bfLo(v.z); a[5] = di * bfHi(v.z);
    a[6] = di * bfLo(v.w); a[7] = di * bfHi(v.w);
  }
  __syncthreads();
  int bc = (int)bucketCnt[c * 16];
  if (bc > CAP) bc = CAP;
  int i0 = c * CAP;
  int wv = t >> 6;
  int lane = t & 63;
  int q = lane >> 3;
  int ql = lane & 7;
  AGG_STREAM(edges, i0, bc, H8, acc, sdi)
  __syncthreads();
  for (int k = t; k < NPB * 8; k += DFT) {  // epilogue: +b2, fp32 store
    int row = k >> 3, c8 = k & 7;
    int g = base + row;
    if (g >= n) continue;
    const float* a = &acc[row * PADW + c8 * 8];
    float4 bv0 = ((const float4*)b2)[2 * c8];
    float4 bv1 = ((const float4*)b2)[2 * c8 + 1];
    float4 o0, o1;
    o0.x = a[0] + bv0.x; o0.y = a[1] + bv0.y; o0.z = a[2] + bv0.z; o0.w = a[3] + bv0.w;
    o1.x = a[4] + bv1.x; o1.y = a[5] + bv1.y; o1.z = a[6] + bv1.z; o1.w = a[7] + bv1.w;
    float* op = out + (size_t)g * HID + c8 * 8;
    *(float4*)op = o0;
    *(float4*)(op + 4) = o1;
  }
}

extern "C" void kernel_launch(void* const* d_in, const int* in_sizes, int n_in,
                              void* d_out, int out_size, void* d_ws, size_t ws_size,
                              hipStream_t stream) {
  const float* x  = (const float*)d_in[0];
  const int*   ei = (const int*)d_in[1];
  const float* ew = (const float*)d_in[2];
  const float* W1 = (const float*)d_in[3];
  const float* b1 = (const float*)d_in[4];
  const float* W2 = (const float*)d_in[5];
  const float* b2 = (const float*)d_in[6];
  float* out = (float*)d_out;

  const int n  = in_sizes[0] / HID;   // 100000
  const int nE = in_sizes[2];         // 1000000
  const int* src = ei;
  const int* dst = ei + nE;

  const int B = (n + NPB - 1) / NPB;  // 782 buckets of 128 nodes
  const int G1  = (nE + DFT * 4 - 1) / (DFT * 4);     // 489 blocks
  const int ept = (nE + G1 * DFT - 1) / (G1 * DFT);   // 4

  // ---- workspace layout (~27 MB) ----
  auto align512 = [](size_t v) { return (v + 511) & ~(size_t)511; };
  char* ws = (char*)d_ws;
  size_t off = 0;
  float* deg         = (float*)(ws + off); off += align512((size_t)n * 4);
  unsigned int* bucketCnt = (unsigned int*)(ws + off); off += align512((size_t)B * 16 * 4);
  size_t zeroSpan = off;  // deg + bucketCnt zeroed in ONE memset
  float* dinv        = (float*)(ws + off); off += align512((size_t)n * 4);
  int2*  edges       = (int2*) (ws + off); off += align512((size_t)B * CAP * 8 + 512);
  unsigned short* P2 = (unsigned short*)(ws + off); off += align512((size_t)n * HID * 2);
  // P1 (12.8 MB bf16) lives in d_out's first half: dead before k_aggL2
  // (the only writer of d_out) runs.
  unsigned short* P1 = (unsigned short*)d_out;

  // ---- 5 dispatches ----
  hipMemsetAsync(ws, 0, zeroSpan, stream);
  k_bucket1<<<G1, DFT, 0, stream>>>(src, dst, ew, bucketCnt, edges, deg, B, ept, nE);
  k_proj<<<B, DFT, 0, stream>>>(x, W1, deg, dinv, P1, n);
  k_aggL1<<<B, DFT, 0, stream>>>(edges, bucketCnt, dinv, (const uint4*)P1, b1, W2, P2, n);
  k_aggL2<<<B, DFT, 0, stream>>>(edges, bucketCnt, dinv, (const uint4*)P2, b2, out, n);
}

// Round 8
// 183.941 us; speedup vs baseline: 5.6057x; 5.6057x over previous
//
#include <hip/hip_runtime.h>

#define HID 64
#define NPB 256    // nodes per bucket (bucket = dst >> 8)
#define CAP 3072   // fixed per-bucket edge capacity: mean 2560, sd ~50 -> ~10 sigma margin
#define DFT 512    // degfill/bucket1 block size (8 waves)
#define RCAP 6     // register-cache records per thread; RCAP*DFT=3072 >= CAP-8 covers whole bucket
#define EPT 4      // bucket1 edges per thread (register-staged single-pass reads)

typedef __attribute__((ext_vector_type(8))) short bf16x8;
typedef __attribute__((ext_vector_type(4))) float f32x4;

__device__ inline float bf2f(unsigned short u) {
  return __uint_as_float((unsigned int)u << 16);
}
__device__ inline unsigned short f2bf(float f) {
  unsigned int u = __float_as_uint(f);
  u += 0x7fff + ((u >> 16) & 1);  // round-to-nearest-even
  return (unsigned short)(u >> 16);
}
__device__ inline float bfLo(unsigned int u) { return __uint_as_float(u << 16); }
__device__ inline float bfHi(unsigned int u) { return __uint_as_float(u & 0xffff0000u); }

// ---- S1 FUSED (hist+reserve+scatter), single-pass reads: (src,dst,ew) staged
// in registers during the histogram pass (12 regs/thread), so the scatter pass
// re-reads nothing. LDS hist -> one global atomicAdd per bucket per block
// (reserve) -> scatter into fixed-capacity bucket regions.
// Bucket c occupies edges[c*CAP .. c*CAP+cnt_c). ----
__global__ __launch_bounds__(DFT) void k_bucket1(const int* __restrict__ src,
                                                 const int* __restrict__ dst,
                                                 const float* __restrict__ ew,
                                                 unsigned int* __restrict__ bucketCnt,  // B*16 padded
                                                 int2* __restrict__ edges,
                                                 int B, int nE) {
  __shared__ unsigned int hist[512];
  hist[threadIdx.x] = 0;
  __syncthreads();
  int base = blockIdx.x * DFT * EPT;
  int d[EPT], s[EPT];
  float w[EPT];
#pragma unroll
  for (int i = 0; i < EPT; ++i) {
    int e = base + i * DFT + threadIdx.x;
    bool ok = e < nE;
    d[i] = ok ? dst[e] : -1;
    s[i] = ok ? src[e] : 0;
    w[i] = ok ? ew[e] : 0.f;
    if (ok) atomicAdd(&hist[(unsigned)d[i] >> 8], 1u);
  }
  __syncthreads();
  for (int c = threadIdx.x; c < B; c += DFT) {
    unsigned int h = hist[c];
    unsigned int b = 0;
    if (h) b = atomicAdd(&bucketCnt[c * 16], h);  // 64B-padded line per bucket
    hist[c] = (unsigned)(c * CAP) + b;            // absolute write cursor
  }
  __syncthreads();
#pragma unroll
  for (int i = 0; i < EPT; ++i) {
    if (d[i] >= 0) {
      int c = (unsigned)d[i] >> 8;
      int slot = (int)atomicAdd(&hist[c], 1u);
      if (slot < (c + 1) * CAP)  // never taken statistically; memory safety only
        edges[slot] = make_int2(s[i] | ((d[i] & 255) << 24), __float_as_int(w[i]));
    }
  }
}

// ---- S2 FUSED (degfill + gemm1): phase A = deg + count + scan + IN-PLACE
// row-sorted rewrite (register-cached, all reads before any write); phase B =
// MFMA gemm over this bucket's 256 rows with dinv in LDS. Out = P1 lives in
// d_out's first half (dead before the final aggregate overwrites d_out).
// rowStart[g+1] = END offset of row g; starts are c*CAP arithmetically.
// 8 zero-sentinel edges pad each bucket for the aggregator's 8-wide tail reads. ----
__global__ __launch_bounds__(DFT) void k_degfillG(int2* __restrict__ edges,
                                                  const unsigned int* __restrict__ bucketCnt,
                                                  const float* __restrict__ X,
                                                  const float* __restrict__ W,
                                                  float* __restrict__ dinv,
                                                  int* __restrict__ rowStart,
                                                  unsigned short* __restrict__ Out, int n) {
  __shared__ float deg[NPB];
  __shared__ int cnt[NPB];
  __shared__ int s[NPB];
  if (threadIdx.x < NPB) {
    deg[threadIdx.x] = 1.0f;  // self-loop weight
    cnt[threadIdx.x] = 0;
  }
  __syncthreads();
  int c = blockIdx.x;
  int i0 = c * CAP;
  int bc = (int)bucketCnt[c * 16];
  if (bc > CAP - 8) bc = CAP - 8;  // never taken; memory safety
  int i1 = i0 + bc;
  int2 rec[RCAP];
  int myCnt = 0;
  for (int i = i0 + threadIdx.x; i < i1; i += DFT) {
    int2 r = edges[i];
#pragma unroll
    for (int k = 0; k < RCAP; ++k)
      if (k == myCnt) rec[k] = r;
    myCnt++;
    int l = (unsigned)r.x >> 24;
    atomicAdd(&deg[l], __int_as_float(r.y));
    atomicAdd(&cnt[l], 1);
  }
  __syncthreads();  // ALL reads of edges[] done before any write below
  int v = 0;
  if (threadIdx.x < NPB) {
    v = cnt[threadIdx.x];
    s[threadIdx.x] = v;
  }
  __syncthreads();
  for (int o = 1; o < NPB; o <<= 1) {
    int t = (threadIdx.x < NPB && threadIdx.x >= (unsigned)o) ? s[threadIdx.x - o] : 0;
    __syncthreads();
    if (threadIdx.x < NPB) s[threadIdx.x] += t;
    __syncthreads();
  }
  if (threadIdx.x < NPB) {
    int rowBase = i0 + s[threadIdx.x] - v;
    float di = rsqrtf(deg[threadIdx.x]);
    int g = c * NPB + threadIdx.x;
    if (g < n) {
      rowStart[g + 1] = i0 + s[threadIdx.x];  // inclusive end of row g
      dinv[g] = di;
    }
    cnt[threadIdx.x] = rowBase;  // reuse as cursor (deg reused as ddst below)
  }
  if (threadIdx.x < 8) edges[i1 + threadIdx.x] = make_int2(0, 0);  // zero sentinels
  __syncthreads();
  if (threadIdx.x < NPB) deg[threadIdx.x] = rsqrtf(deg[threadIdx.x]);  // ddst = di
  __syncthreads();
#pragma unroll
  for (int k = 0; k < RCAP; ++k) {
    if (k < myCnt) {
      int2 r = rec[k];
      int l = (unsigned)r.x >> 24;
      int pos = atomicAdd(&cnt[l], 1);
      float norm = __int_as_float(r.y) * deg[l];  // ew * dinv[dst]
      edges[pos] = make_int2(r.x & 0xFFFFFF, __float_as_int(norm));
    }
  }
  // ---- phase B: gemm1 for rows [c*256, c*256+256). deg[] holds di. ----
  __syncthreads();
  int wv = threadIdx.x >> 6;
  int lane = threadIdx.x & 63;
  int m16 = lane & 15;
  int q = lane >> 4;
  bf16x8 Bb[4][2], Br[4][2];
#pragma unroll
  for (int nt = 0; nt < 4; ++nt)
#pragma unroll
    for (int kh = 0; kh < 2; ++kh) {
      int ncol = nt * 16 + m16;
      int k0 = kh * 32 + q * 8;
#pragma unroll
      for (int j = 0; j < 8; ++j) {
        float w = W[(k0 + j) * HID + ncol];
        unsigned short wb = f2bf(w);
        Bb[nt][kh][j] = (short)wb;
        Br[nt][kh][j] = (short)f2bf(w - bf2f(wb));
      }
    }
#pragma unroll
  for (int sub = 0; sub < 2; ++sub) {
    int slice = sub * 8 + wv;  // 16 slices of 16 rows over 8 waves x 2 iters
    int rowBase2 = c * 256 + slice * 16;
    if (rowBase2 >= n) continue;
    int mc = rowBase2 + m16;
    if (mc >= n) mc = n - 1;
    bf16x8 A[2];
    const float* Xp = X + (size_t)mc * HID;
#pragma unroll
    for (int kh = 0; kh < 2; ++kh) {
      f32x4 x0 = *(const f32x4*)(Xp + kh * 32 + q * 8);
      f32x4 x1 = *(const f32x4*)(Xp + kh * 32 + q * 8 + 4);
#pragma unroll
      for (int j = 0; j < 4; ++j) {
        A[kh][j] = (short)f2bf(x0[j]);
        A[kh][4 + j] = (short)f2bf(x1[j]);
      }
    }
    float dv = deg[slice * 16 + m16];  // di for row rowBase2+m16 (LDS)
#pragma unroll
    for (int nt = 0; nt < 4; ++nt) {
      f32x4 acc = {0.f, 0.f, 0.f, 0.f};
      // swapped operands -> D transposed: lane holds row rowBase2+m16,
      // cols nt*16 + q*4 + r  => one contiguous 8B bf16x4 store per nt
      acc = __builtin_amdgcn_mfma_f32_16x16x32_bf16(Bb[nt][0], A[0], acc, 0, 0, 0);
      acc = __builtin_amdgcn_mfma_f32_16x16x32_bf16(Bb[nt][1], A[1], acc, 0, 0, 0);
      acc = __builtin_amdgcn_mfma_f32_16x16x32_bf16(Br[nt][0], A[0], acc, 0, 0, 0);
      acc = __builtin_amdgcn_mfma_f32_16x16x32_bf16(Br[nt][1], A[1], acc, 0, 0, 0);
      if (rowBase2 + m16 < n) {
        ushort4 o;
        o.x = f2bf(acc[0] * dv);
        o.y = f2bf(acc[1] * dv);
        o.z = f2bf(acc[2] * dv);
        o.w = f2bf(acc[3] * dv);
        *(ushort4*)(&Out[(size_t)(rowBase2 + m16) * HID + nt * 16 + q * 4]) = o;
      }
    }
  }
}

// 8-wide edge step: 4 independent int4 edge loads + 8 independent H-row
// gathers per iteration. Accumulation order per channel unchanged.
#define AGG_STEP8(EDG, H8P, QL, E0, E1, B2)                                   \
  int4 p0 = *(const int4*)((EDG) + (B2));                                     \
  int4 p1 = *(const int4*)((EDG) + (B2) + 2);                                 \
  int4 p2 = *(const int4*)((EDG) + (B2) + 4);                                 \
  int4 p3 = *(const int4*)((EDG) + (B2) + 6);                                 \
  uint4 h0 = (H8P)[(size_t)(unsigned)p0.x * 8u + (QL)];                       \
  uint4 h1 = (H8P)[(size_t)(unsigned)p0.z * 8u + (QL)];                       \
  uint4 h2 = (H8P)[(size_t)(unsigned)p1.x * 8u + (QL)];                       \
  uint4 h3 = (H8P)[(size_t)(unsigned)p1.z * 8u + (QL)];                       \
  uint4 h4 = (H8P)[(size_t)(unsigned)p2.x * 8u + (QL)];                       \
  uint4 h5 = (H8P)[(size_t)(unsigned)p2.z * 8u + (QL)];                       \
  uint4 h6 = (H8P)[(size_t)(unsigned)p3.x * 8u + (QL)];                       \
  uint4 h7 = (H8P)[(size_t)(unsigned)p3.z * 8u + (QL)];                       \
  float n0 = ((B2) >= (E0)) ? __int_as_float(p0.y) : 0.f;                     \
  float n1 = ((B2) + 1 < (E1)) ? __int_as_float(p0.w) : 0.f;                  \
  float n2 = ((B2) + 2 < (E1)) ? __int_as_float(p1.y) : 0.f;                  \
  float n3 = ((B2) + 3 < (E1)) ? __int_as_float(p1.w) : 0.f;                  \
  float n4 = ((B2) + 4 < (E1)) ? __int_as_float(p2.y) : 0.f;                  \
  float n5 = ((B2) + 5 < (E1)) ? __int_as_float(p2.w) : 0.f;                  \
  float n6 = ((B2) + 6 < (E1)) ? __int_as_float(p3.y) : 0.f;                  \
  float n7 = ((B2) + 7 < (E1)) ? __int_as_float(p3.w) : 0.f;                  \
  a0 = fmaf(n0, bfLo(h0.x), a0); a1 = fmaf(n0, bfHi(h0.x), a1);               \
  a2 = fmaf(n0, bfLo(h0.y), a2); a3 = fmaf(n0, bfHi(h0.y), a3);               \
  a4 = fmaf(n0, bfLo(h0.z), a4); a5 = fmaf(n0, bfHi(h0.z), a5);               \
  a6 = fmaf(n0, bfLo(h0.w), a6); a7 = fmaf(n0, bfHi(h0.w), a7);               \
  a0 = fmaf(n1, bfLo(h1.x), a0); a1 = fmaf(n1, bfHi(h1.x), a1);               \
  a2 = fmaf(n1, bfLo(h1.y), a2); a3 = fmaf(n1, bfHi(h1.y), a3);               \
  a4 = fmaf(n1, bfLo(h1.z), a4); a5 = fmaf(n1, bfHi(h1.z), a5);               \
  a6 = fmaf(n1, bfLo(h1.w), a6); a7 = fmaf(n1, bfHi(h1.w), a7);               \
  a0 = fmaf(n2, bfLo(h2.x), a0); a1 = fmaf(n2, bfHi(h2.x), a1);               \
  a2 = fmaf(n2, bfLo(h2.y), a2); a3 = fmaf(n2, bfHi(h2.y), a3);               \
  a4 = fmaf(n2, bfLo(h2.z), a4); a5 = fmaf(n2, bfHi(h2.z), a5);               \
  a6 = fmaf(n2, bfLo(h2.w), a6); a7 = fmaf(n2, bfHi(h2.w), a7);               \
  a0 = fmaf(n3, bfLo(h3.x), a0); a1 = fmaf(n3, bfHi(h3.x), a1);               \
  a2 = fmaf(n3, bfLo(h3.y), a2); a3 = fmaf(n3, bfHi(h3.y), a3);               \
  a4 = fmaf(n3, bfLo(h3.z), a4); a5 = fmaf(n3, bfHi(h3.z), a5);               \
  a6 = fmaf(n3, bfLo(h3.w), a6); a7 = fmaf(n3, bfHi(h3.w), a7);               \
  a0 = fmaf(n4, bfLo(h4.x), a0); a1 = fmaf(n4, bfHi(h4.x), a1);               \
  a2 = fmaf(n4, bfLo(h4.y), a2); a3 = fmaf(n4, bfHi(h4.y), a3);               \
  a4 = fmaf(n4, bfLo(h4.z), a4); a5 = fmaf(n4, bfHi(h4.z), a5);               \
  a6 = fmaf(n4, bfLo(h4.w), a6); a7 = fmaf(n4, bfHi(h4.w), a7);               \
  a0 = fmaf(n5, bfLo(h5.x), a0); a1 = fmaf(n5, bfHi(h5.x), a1);               \
  a2 = fmaf(n5, bfLo(h5.y), a2); a3 = fmaf(n5, bfHi(h5.y), a3);               \
  a4 = fmaf(n5, bfLo(h5.z), a4); a5 = fmaf(n5, bfHi(h5.z), a5);               \
  a6 = fmaf(n5, bfLo(h5.w), a6); a7 = fmaf(n5, bfHi(h5.w), a7);               \
  a0 = fmaf(n6, bfLo(h6.x), a0); a1 = fmaf(n6, bfHi(h6.x), a1);               \
  a2 = fmaf(n6, bfLo(h6.y), a2); a3 = fmaf(n6, bfHi(h6.y), a3);               \
  a4 = fmaf(n6, bfLo(h6.z), a4); a5 = fmaf(n6, bfHi(h6.z), a5);               \
  a6 = fmaf(n6, bfLo(h6.w), a6); a7 = fmaf(n6, bfHi(h6.w), a7);               \
  a0 = fmaf(n7, bfLo(h7.x), a0); a1 = fmaf(n7, bfHi(h7.x), a1);               \
  a2 = fmaf(n7, bfLo(h7.y), a2); a3 = fmaf(n7, bfHi(h7.y), a3);               \
  a4 = fmaf(n7, bfLo(h7.z), a4); a5 = fmaf(n7, bfHi(h7.z), a5);               \
  a6 = fmaf(n7, bfLo(h7.w), a6); a7 = fmaf(n7, bfHi(h7.w), a7);

// ---- FUSED layer-1 aggregate + layer-2 projection: each block owns 32 nodes
// (4 waves x 8). Wave computes ReLU(agg+b1) rows -> 5KB LDS -> each wave runs
// one 16-col n-tile of the 32-row MFMA gemm (W2 frags, transposed-D stores).
// Writes P2 = bf16(dinv*(h1@W2)) to workspace; never touches d_out (P1 src). ----
__global__ __launch_bounds__(256) void k_aggG(const int2* __restrict__ edges,
                                              const int* __restrict__ rowStart,
                                              const float* __restrict__ dinv,
                                              const uint4* __restrict__ H8,  // P1: 8 x uint4 per node
                                              const float* __restrict__ bias,
                                              const float* __restrict__ W,   // W2
                                              unsigned short* __restrict__ Out,  // P2
                                              int n) {
  __shared__ uint4 sh[32][10];  // [row][uint4 col], padded 8->10
  __shared__ float sdi[32];
  int wv = threadIdx.x >> 6;
  int lane = threadIdx.x & 63;
  int q = lane >> 3;    // which of 8 nodes in this wave
  int ql = lane & 7;    // channels 8*ql .. 8*ql+7
  int base = blockIdx.x * 32;
  int node = base + wv * 8 + q;
  if (node < n) {
    int e0 = rowStart[node];
    if ((node & 255) == 0) e0 = (node >> 8) * CAP;  // bucket start (rowStart[g] holds ends)
    int e1 = rowStart[node + 1];
    float di = dinv[node];
    uint4 su = H8[(size_t)node * 8 + ql];
    float a0 = di * bfLo(su.x), a1 = di * bfHi(su.x);
    float a2 = di * bfLo(su.y), a3 = di * bfHi(su.y);
    float a4 = di * bfLo(su.z), a5 = di * bfHi(su.z);
    float a6 = di * bfLo(su.w), a7 = di * bfHi(su.w);
    for (int b2 = e0 & ~1; b2 < e1; b2 += 8) {
      AGG_STEP8(edges, H8, ql, e0, e1, b2)
    }
    float4 bv0 = ((const float4*)bias)[2 * ql];
    float4 bv1 = ((const float4*)bias)[2 * ql + 1];
    a0 = fmaxf(a0 + bv0.x, 0.f); a1 = fmaxf(a1 + bv0.y, 0.f);
    a2 = fmaxf(a2 + bv0.z, 0.f); a3 = fmaxf(a3 + bv0.w, 0.f);
    a4 = fmaxf(a4 + bv1.x, 0.f); a5 = fmaxf(a5 + bv1.y, 0.f);
    a6 = fmaxf(a6 + bv1.z, 0.f); a7 = fmaxf(a7 + bv1.w, 0.f);
    uint4 o;
    o.x = (unsigned)f2bf(a0) | ((unsigned)f2bf(a1) << 16);
    o.y = (unsigned)f2bf(a2) | ((unsigned)f2bf(a3) << 16);
    o.z = (unsigned)f2bf(a4) | ((unsigned)f2bf(a5) << 16);
    o.w = (unsigned)f2bf(a6) | ((unsigned)f2bf(a7) << 16);
    sh[wv * 8 + q][ql] = o;
    if (ql == 0) sdi[wv * 8 + q] = di;
  } else {
    sh[wv * 8 + q][ql] = make_uint4(0, 0, 0, 0);
    if (ql == 0) sdi[wv * 8 + q] = 0.f;
  }
  __syncthreads();
  // ---- gemm2 phase: 32 rows from LDS; this wave owns n-tile nt = wv ----
  int m16 = lane & 15;
  int qq = lane >> 4;
  bf16x8 Bb[2], Br[2];
#pragma unroll
  for (int kh = 0; kh < 2; ++kh) {
    int ncol = wv * 16 + m16;
    int k0 = kh * 32 + qq * 8;
#pragma unroll
    for (int j = 0; j < 8; ++j) {
      float w = W[(k0 + j) * HID + ncol];  // L1-hot (16 KB)
      unsigned short wb = f2bf(w);
      Bb[kh][j] = (short)wb;
      Br[kh][j] = (short)f2bf(w - bf2f(wb));
    }
  }
#pragma unroll
  for (int rt = 0; rt < 2; ++rt) {
    int row = rt * 16 + m16;
    bf16x8 A0 = *(const bf16x8*)&sh[row][qq];      // k = qq*8 .. +7
    bf16x8 A1 = *(const bf16x8*)&sh[row][4 + qq];  // k = 32 + qq*8 .. +7
    f32x4 acc = {0.f, 0.f, 0.f, 0.f};
    acc = __builtin_amdgcn_mfma_f32_16x16x32_bf16(Bb[0], A0, acc, 0, 0, 0);
    acc = __builtin_amdgcn_mfma_f32_16x16x32_bf16(Bb[1], A1, acc, 0, 0, 0);
    acc = __builtin_amdgcn_mfma_f32_16x16x32_bf16(Br[0], A0, acc, 0, 0, 0);
    acc = __builtin_amdgcn_mfma_f32_16x16x32_bf16(Br[1], A1, acc, 0, 0, 0);
    int gnode = base + row;
    if (gnode < n) {
      float dv = sdi[row];
      ushort4 o;
      o.x = f2bf(acc[0] * dv);
      o.y = f2bf(acc[1] * dv);
      o.z = f2bf(acc[2] * dv);
      o.w = f2bf(acc[3] * dv);
      *(ushort4*)(&Out[(size_t)gnode * HID + wv * 16 + qq * 4]) = o;
    }
  }
}

// ---- CSR aggregate (layer 2): 8 nodes per wave, float4 output + bias ----
__global__ __launch_bounds__(256) void k_agg8f(const int2* __restrict__ edges,
                                               const int* __restrict__ rowStart,
                                               const float* __restrict__ dinv,
                                               const uint4* __restrict__ H8,  // P2
                                               const float* __restrict__ bias,
                                               float* __restrict__ outp, int n) {
  int gwave = (blockIdx.x * 256 + threadIdx.x) >> 6;
  int lane = threadIdx.x & 63;
  int q = lane >> 3;
  int ql = lane & 7;
  int node = gwave * 8 + q;
  if (node >= n) return;
  int e0 = rowStart[node];
  if ((node & 255) == 0) e0 = (node >> 8) * CAP;
  int e1 = rowStart[node + 1];
  float di = dinv[node];
  uint4 su = H8[(size_t)node * 8 + ql];
  float a0 = di * bfLo(su.x), a1 = di * bfHi(su.x);
  float a2 = di * bfLo(su.y), a3 = di * bfHi(su.y);
  float a4 = di * bfLo(su.z), a5 = di * bfHi(su.z);
  float a6 = di * bfLo(su.w), a7 = di * bfHi(su.w);
  for (int b2 = e0 & ~1; b2 < e1; b2 += 8) {
    AGG_STEP8(edges, H8, ql, e0, e1, b2)
  }
  float4 bv0 = ((const float4*)bias)[2 * ql];
  float4 bv1 = ((const float4*)bias)[2 * ql + 1];
  float4 o0, o1;
  o0.x = a0 + bv0.x; o0.y = a1 + bv0.y; o0.z = a2 + bv0.z; o0.w = a3 + bv0.w;
  o1.x = a4 + bv1.x; o1.y = a5 + bv1.y; o1.z = a6 + bv1.z; o1.w = a7 + bv1.w;
  ((float4*)outp)[(size_t)node * 16 + 2 * ql] = o0;
  ((float4*)outp)[(size_t)node * 16 + 2 * ql + 1] = o1;
}

extern "C" void kernel_launch(void* const* d_in, const int* in_sizes, int n_in,
                              void* d_out, int out_size, void* d_ws, size_t ws_size,
                              hipStream_t stream) {
  const float* x  = (const float*)d_in[0];
  const int*   ei = (const int*)d_in[1];
  const float* ew = (const float*)d_in[2];
  const float* W1 = (const float*)d_in[3];
  const float* b1 = (const float*)d_in[4];
  const float* W2 = (const float*)d_in[5];
  const float* b2 = (const float*)d_in[6];
  float* out = (float*)d_out;

  const int n  = in_sizes[0] / HID;   // 100000
  const int nE = in_sizes[2];         // 1000000
  const int* src = ei;
  const int* dst = ei + nE;

  const int B = (n + NPB - 1) / NPB;               // 391 buckets
  const int G1 = (nE + DFT * EPT - 1) / (DFT * EPT);  // 489 blocks

  // ---- workspace layout (~23.2 MB) ----
  auto align512 = [](size_t v) { return (v + 511) & ~(size_t)511; };
  char* ws = (char*)d_ws;
  size_t off = 0;
  float* dinv        = (float*)(ws + off); off += align512((size_t)n * 4);
  int*   rowStart    = (int*)  (ws + off); off += align512((size_t)(n + 1) * 4);
  unsigned int* bucketCnt = (unsigned int*)(ws + off); off += align512((size_t)B * 16 * 4);
  int2*  edges       = (int2*) (ws + off); off += align512((size_t)B * CAP * 8 + 128);
  unsigned short* P2 = (unsigned short*)(ws + off); off += align512((size_t)n * HID * 2);
  // P1 (12.8 MB bf16) lives in d_out's first half: dead before k_agg8f
  // (the only writer of d_out) runs.
  unsigned short* P1 = (unsigned short*)d_out;

  const int aggBlocks = (n + 31) / 32;  // 32 nodes per block (4 waves x 8)

  // ---- 5 dispatches total ----
  hipMemsetAsync(bucketCnt, 0, (size_t)B * 16 * 4, stream);
  k_bucket1<<<G1, DFT, 0, stream>>>(src, dst, ew, bucketCnt, edges, B, nE);
  k_degfillG<<<B, DFT, 0, stream>>>(edges, bucketCnt, x, W1, dinv, rowStart, P1, n);

  // layer-1 aggregate fused with layer-2 projection (P1 -> P2)
  k_aggG<<<aggBlocks, 256, 0, stream>>>(edges, rowStart, dinv,
                                        (const uint4*)P1, b1, W2, P2, n);

  // layer-2 aggregate -> final output
  k_agg8f<<<aggBlocks, 256, 0, stream>>>(edges, rowStart, dinv,
                                         (const uint4*)P2, b2, out, n);
}

// Round 9
// 180.703 us; speedup vs baseline: 5.7061x; 1.0179x over previous
//
#include <hip/hip_runtime.h>

#define HID 64
#define NPB 256    // nodes per bucket (bucket = dst >> 8)
#define CAP 3072   // fixed per-bucket edge capacity: mean 2560, sd ~50 -> ~10 sigma margin
#define DFT 512    // degfill/bucket1 block size (8 waves)
#define RCAP 6     // register-cache records per thread; RCAP*DFT=3072 >= CAP-8 covers whole bucket

typedef __attribute__((ext_vector_type(8))) short bf16x8;
typedef __attribute__((ext_vector_type(4))) float f32x4;

__device__ inline float bf2f(unsigned short u) {
  return __uint_as_float((unsigned int)u << 16);
}
__device__ inline unsigned short f2bf(float f) {
  unsigned int u = __float_as_uint(f);
  u += 0x7fff + ((u >> 16) & 1);  // round-to-nearest-even
  return (unsigned short)(u >> 16);
}
__device__ inline float bfLo(unsigned int u) { return __uint_as_float(u << 16); }
__device__ inline float bfHi(unsigned int u) { return __uint_as_float(u & 0xffff0000u); }

// ---- S1 FUSED (hist+reserve+scatter): LDS hist -> one global atomicAdd per
// bucket per block (reserve) -> scatter into fixed-capacity bucket regions.
// Bucket c occupies edges[c*CAP .. c*CAP+cnt_c). ----
__global__ __launch_bounds__(DFT) void k_bucket1(const int* __restrict__ src,
                                                 const int* __restrict__ dst,
                                                 const float* __restrict__ ew,
                                                 unsigned int* __restrict__ bucketCnt,  // B*16 padded
                                                 int2* __restrict__ edges,
                                                 int B, int ept, int nE) {
  __shared__ unsigned int hist[512];
  hist[threadIdx.x] = 0;
  __syncthreads();
  int base = blockIdx.x * DFT * ept;
  for (int i = 0; i < ept; ++i) {
    int e = base + i * DFT + threadIdx.x;
    if (e < nE) atomicAdd(&hist[(unsigned)dst[e] >> 8], 1u);
  }
  __syncthreads();
  for (int c = threadIdx.x; c < B; c += DFT) {
    unsigned int h = hist[c];
    unsigned int b = 0;
    if (h) b = atomicAdd(&bucketCnt[c * 16], h);  // 64B-padded line per bucket
    hist[c] = (unsigned)(c * CAP) + b;            // absolute write cursor
  }
  __syncthreads();
  for (int i = 0; i < ept; ++i) {
    int e = base + i * DFT + threadIdx.x;
    if (e < nE) {
      int d = dst[e];
      int c = (unsigned)d >> 8;
      int slot = (int)atomicAdd(&hist[c], 1u);
      if (slot < (c + 1) * CAP)  // never taken statistically; memory safety only
        edges[slot] = make_int2(src[e] | ((d & 255) << 24), __float_as_int(ew[e]));
    }
  }
}

// ---- S2 FUSED (degfill + gemm1): phase A = deg + count + scan + IN-PLACE
// row-sorted rewrite (register-cached, all reads before any write); phase B =
// MFMA gemm over this bucket's 256 rows with dinv in LDS. Out = P1 lives in
// d_out's first half (dead before the final aggregate overwrites d_out).
// rowStart[g+1] = END offset of row g; starts are c*CAP arithmetically.
// 8 zero-sentinel edges pad each bucket for the aggregator's 8-wide tail reads. ----
__global__ __launch_bounds__(DFT) void k_degfillG(int2* __restrict__ edges,
                                                  const unsigned int* __restrict__ bucketCnt,
                                                  const float* __restrict__ X,
                                                  const float* __restrict__ W,
                                                  float* __restrict__ dinv,
                                                  int* __restrict__ rowStart,
                                                  unsigned short* __restrict__ Out, int n) {
  __shared__ float deg[NPB];
  __shared__ int cnt[NPB];
  __shared__ int s[NPB];
  if (threadIdx.x < NPB) {
    deg[threadIdx.x] = 1.0f;  // self-loop weight
    cnt[threadIdx.x] = 0;
  }
  __syncthreads();
  int c = blockIdx.x;
  int i0 = c * CAP;
  int bc = (int)bucketCnt[c * 16];
  if (bc > CAP - 8) bc = CAP - 8;  // never taken; memory safety
  int i1 = i0 + bc;
  int2 rec[RCAP];
  int myCnt = 0;
  for (int i = i0 + threadIdx.x; i < i1; i += DFT) {
    int2 r = edges[i];
#pragma unroll
    for (int k = 0; k < RCAP; ++k)
      if (k == myCnt) rec[k] = r;
    myCnt++;
    int l = (unsigned)r.x >> 24;
    atomicAdd(&deg[l], __int_as_float(r.y));
    atomicAdd(&cnt[l], 1);
  }
  __syncthreads();  // ALL reads of edges[] done before any write below
  int v = 0;
  if (threadIdx.x < NPB) {
    v = cnt[threadIdx.x];
    s[threadIdx.x] = v;
  }
  __syncthreads();
  for (int o = 1; o < NPB; o <<= 1) {
    int t = (threadIdx.x < NPB && threadIdx.x >= (unsigned)o) ? s[threadIdx.x - o] : 0;
    __syncthreads();
    if (threadIdx.x < NPB) s[threadIdx.x] += t;
    __syncthreads();
  }
  if (threadIdx.x < NPB) {
    int rowBase = i0 + s[threadIdx.x] - v;
    float di = rsqrtf(deg[threadIdx.x]);
    int g = c * NPB + threadIdx.x;
    if (g < n) {
      rowStart[g + 1] = i0 + s[threadIdx.x];  // inclusive end of row g
      dinv[g] = di;
    }
    cnt[threadIdx.x] = rowBase;  // reuse as cursor (deg reused as ddst below)
  }
  if (threadIdx.x < 8) edges[i1 + threadIdx.x] = make_int2(0, 0);  // zero sentinels
  __syncthreads();
  if (threadIdx.x < NPB) deg[threadIdx.x] = rsqrtf(deg[threadIdx.x]);  // ddst = di
  __syncthreads();
#pragma unroll
  for (int k = 0; k < RCAP; ++k) {
    if (k < myCnt) {
      int2 r = rec[k];
      int l = (unsigned)r.x >> 24;
      int pos = atomicAdd(&cnt[l], 1);
      float norm = __int_as_float(r.y) * deg[l];  // ew * dinv[dst]
      edges[pos] = make_int2(r.x & 0xFFFFFF, __float_as_int(norm));
    }
  }
  // ---- phase B: gemm1 for rows [c*256, c*256+256). deg[] holds di. ----
  __syncthreads();
  int wv = threadIdx.x >> 6;
  int lane = threadIdx.x & 63;
  int m16 = lane & 15;
  int q = lane >> 4;
  bf16x8 Bb[4][2], Br[4][2];
#pragma unroll
  for (int nt = 0; nt < 4; ++nt)
#pragma unroll
    for (int kh = 0; kh < 2; ++kh) {
      int ncol = nt * 16 + m16;
      int k0 = kh * 32 + q * 8;
#pragma unroll
      for (int j = 0; j < 8; ++j) {
        float w = W[(k0 + j) * HID + ncol];
        unsigned short wb = f2bf(w);
        Bb[nt][kh][j] = (short)wb;
        Br[nt][kh][j] = (short)f2bf(w - bf2f(wb));
      }
    }
#pragma unroll
  for (int sub = 0; sub < 2; ++sub) {
    int slice = sub * 8 + wv;  // 16 slices of 16 rows over 8 waves x 2 iters
    int rowBase2 = c * 256 + slice * 16;
    if (rowBase2 >= n) continue;
    int mc = rowBase2 + m16;
    if (mc >= n) mc = n - 1;
    bf16x8 A[2];
    const float* Xp = X + (size_t)mc * HID;
#pragma unroll
    for (int kh = 0; kh < 2; ++kh) {
      f32x4 x0 = *(const f32x4*)(Xp + kh * 32 + q * 8);
      f32x4 x1 = *(const f32x4*)(Xp + kh * 32 + q * 8 + 4);
#pragma unroll
      for (int j = 0; j < 4; ++j) {
        A[kh][j] = (short)f2bf(x0[j]);
        A[kh][4 + j] = (short)f2bf(x1[j]);
      }
    }
    float dv = deg[slice * 16 + m16];  // di for row rowBase2+m16 (LDS)
#pragma unroll
    for (int nt = 0; nt < 4; ++nt) {
      f32x4 acc = {0.f, 0.f, 0.f, 0.f};
      // swapped operands -> D transposed: lane holds row rowBase2+m16,
      // cols nt*16 + q*4 + r  => one contiguous 8B bf16x4 store per nt
      acc = __builtin_amdgcn_mfma_f32_16x16x32_bf16(Bb[nt][0], A[0], acc, 0, 0, 0);
      acc = __builtin_amdgcn_mfma_f32_16x16x32_bf16(Bb[nt][1], A[1], acc, 0, 0, 0);
      acc = __builtin_amdgcn_mfma_f32_16x16x32_bf16(Br[nt][0], A[0], acc, 0, 0, 0);
      acc = __builtin_amdgcn_mfma_f32_16x16x32_bf16(Br[nt][1], A[1], acc, 0, 0, 0);
      if (rowBase2 + m16 < n) {
        ushort4 o;
        o.x = f2bf(acc[0] * dv);
        o.y = f2bf(acc[1] * dv);
        o.z = f2bf(acc[2] * dv);
        o.w = f2bf(acc[3] * dv);
        *(ushort4*)(&Out[(size_t)(rowBase2 + m16) * HID + nt * 16 + q * 4]) = o;
      }
    }
  }
}

// 8-wide edge step with GATHER MASKING: invalid tail slots (past e1 / below e0)
// redirect their H-row gather to row 0 (L1-hot) instead of a random neighbor-row
// record -> kills ~35% of random L2-miss gather traffic. norm already 0 there,
// so arithmetic is bit-identical.
#define AGG_STEP8(EDG, H8P, QL, E0, E1, B2)                                   \
  int4 p0 = *(const int4*)((EDG) + (B2));                                     \
  int4 p1 = *(const int4*)((EDG) + (B2) + 2);                                 \
  int4 p2 = *(const int4*)((EDG) + (B2) + 4);                                 \
  int4 p3 = *(const int4*)((EDG) + (B2) + 6);                                 \
  bool v0 = (B2) >= (E0);                                                     \
  bool v1 = (B2) + 1 < (E1);                                                  \
  bool v2 = (B2) + 2 < (E1);                                                  \
  bool v3 = (B2) + 3 < (E1);                                                  \
  bool v4 = (B2) + 4 < (E1);                                                  \
  bool v5 = (B2) + 5 < (E1);                                                  \
  bool v6 = (B2) + 6 < (E1);                                                  \
  bool v7 = (B2) + 7 < (E1);                                                  \
  uint4 h0 = (H8P)[(size_t)(v0 ? (unsigned)p0.x : 0u) * 8u + (QL)];           \
  uint4 h1 = (H8P)[(size_t)(v1 ? (unsigned)p0.z : 0u) * 8u + (QL)];           \
  uint4 h2 = (H8P)[(size_t)(v2 ? (unsigned)p1.x : 0u) * 8u + (QL)];           \
  uint4 h3 = (H8P)[(size_t)(v3 ? (unsigned)p1.z : 0u) * 8u + (QL)];           \
  uint4 h4 = (H8P)[(size_t)(v4 ? (unsigned)p2.x : 0u) * 8u + (QL)];           \
  uint4 h5 = (H8P)[(size_t)(v5 ? (unsigned)p2.z : 0u) * 8u + (QL)];           \
  uint4 h6 = (H8P)[(size_t)(v6 ? (unsigned)p3.x : 0u) * 8u + (QL)];           \
  uint4 h7 = (H8P)[(size_t)(v7 ? (unsigned)p3.z : 0u) * 8u + (QL)];           \
  float n0 = v0 ? __int_as_float(p0.y) : 0.f;                                 \
  float n1 = v1 ? __int_as_float(p0.w) : 0.f;                                 \
  float n2 = v2 ? __int_as_float(p1.y) : 0.f;                                 \
  float n3 = v3 ? __int_as_float(p1.w) : 0.f;                                 \
  float n4 = v4 ? __int_as_float(p2.y) : 0.f;                                 \
  float n5 = v5 ? __int_as_float(p2.w) : 0.f;                                 \
  float n6 = v6 ? __int_as_float(p3.y) : 0.f;                                 \
  float n7 = v7 ? __int_as_float(p3.w) : 0.f;                                 \
  a0 = fmaf(n0, bfLo(h0.x), a0); a1 = fmaf(n0, bfHi(h0.x), a1);               \
  a2 = fmaf(n0, bfLo(h0.y), a2); a3 = fmaf(n0, bfHi(h0.y), a3);               \
  a4 = fmaf(n0, bfLo(h0.z), a4); a5 = fmaf(n0, bfHi(h0.z), a5);               \
  a6 = fmaf(n0, bfLo(h0.w), a6); a7 = fmaf(n0, bfHi(h0.w), a7);               \
  a0 = fmaf(n1, bfLo(h1.x), a0); a1 = fmaf(n1, bfHi(h1.x), a1);               \
  a2 = fmaf(n1, bfLo(h1.y), a2); a3 = fmaf(n1, bfHi(h1.y), a3);               \
  a4 = fmaf(n1, bfLo(h1.z), a4); a5 = fmaf(n1, bfHi(h1.z), a5);               \
  a6 = fmaf(n1, bfLo(h1.w), a6); a7 = fmaf(n1, bfHi(h1.w), a7);               \
  a0 = fmaf(n2, bfLo(h2.x), a0); a1 = fmaf(n2, bfHi(h2.x), a1);               \
  a2 = fmaf(n2, bfLo(h2.y), a2); a3 = fmaf(n2, bfHi(h2.y), a3);               \
  a4 = fmaf(n2, bfLo(h2.z), a4); a5 = fmaf(n2, bfHi(h2.z), a5);               \
  a6 = fmaf(n2, bfLo(h2.w), a6); a7 = fmaf(n2, bfHi(h2.w), a7);               \
  a0 = fmaf(n3, bfLo(h3.x), a0); a1 = fmaf(n3, bfHi(h3.x), a1);               \
  a2 = fmaf(n3, bfLo(h3.y), a2); a3 = fmaf(n3, bfHi(h3.y), a3);               \
  a4 = fmaf(n3, bfLo(h3.z), a4); a5 = fmaf(n3, bfHi(h3.z), a5);               \
  a6 = fmaf(n3, bfLo(h3.w), a6); a7 = fmaf(n3, bfHi(h3.w), a7);               \
  a0 = fmaf(n4, bfLo(h4.x), a0); a1 = fmaf(n4, bfHi(h4.x), a1);               \
  a2 = fmaf(n4, bfLo(h4.y), a2); a3 = fmaf(n4, bfHi(h4.y), a3);               \
  a4 = fmaf(n4, bfLo(h4.z), a4); a5 = fmaf(n4, bfHi(h4.z), a5);               \
  a6 = fmaf(n4, bfLo(h4.w), a6); a7 = fmaf(n4, bfHi(h4.w), a7);               \
  a0 = fmaf(n5, bfLo(h5.x), a0); a1 = fmaf(n5, bfHi(h5.x), a1);               \
  a2 = fmaf(n5, bfLo(h5.y), a2); a3 = fmaf(n5, bfHi(h5.y), a3);               \
  a4 = fmaf(n5, bfLo(h5.z), a4); a5 = fmaf(n5, bfHi(h5.z), a5);               \
  a6 = fmaf(n5, bfLo(h5.w), a6); a7 = fmaf(n5, bfHi(h5.w), a7);               \
  a0 = fmaf(n6, bfLo(h6.x), a0); a1 = fmaf(n6, bfHi(h6.x), a1);               \
  a2 = fmaf(n6, bfLo(h6.y), a2); a3 = fmaf(n6, bfHi(h6.y), a3);               \
  a4 = fmaf(n6, bfLo(h6.z), a4); a5 = fmaf(n6, bfHi(h6.z), a5);               \
  a6 = fmaf(n6, bfLo(h6.w), a6); a7 = fmaf(n6, bfHi(h6.w), a7);               \
  a0 = fmaf(n7, bfLo(h7.x), a0); a1 = fmaf(n7, bfHi(h7.x), a1);               \
  a2 = fmaf(n7, bfLo(h7.y), a2); a3 = fmaf(n7, bfHi(h7.y), a3);               \
  a4 = fmaf(n7, bfLo(h7.z), a4); a5 = fmaf(n7, bfHi(h7.z), a5);               \
  a6 = fmaf(n7, bfLo(h7.w), a6); a7 = fmaf(n7, bfHi(h7.w), a7);

// ---- FUSED layer-1 aggregate + layer-2 projection: each block owns 32 nodes
// (4 waves x 8). Wave computes ReLU(agg+b1) rows -> 5KB LDS -> each wave runs
// one 16-col n-tile of the 32-row MFMA gemm (W2 frags, transposed-D stores).
// Writes P2 = bf16(dinv*(h1@W2)) to workspace; never touches d_out (P1 src). ----
__global__ __launch_bounds__(256) void k_aggG(const int2* __restrict__ edges,
                                              const int* __restrict__ rowStart,
                                              const float* __restrict__ dinv,
                                              const uint4* __restrict__ H8,  // P1: 8 x uint4 per node
                                              const float* __restrict__ bias,
                                              const float* __restrict__ W,   // W2
                                              unsigned short* __restrict__ Out,  // P2
                                              int n) {
  __shared__ uint4 sh[32][10];  // [row][uint4 col], padded 8->10
  __shared__ float sdi[32];
  int wv = threadIdx.x >> 6;
  int lane = threadIdx.x & 63;
  int q = lane >> 3;    // which of 8 nodes in this wave
  int ql = lane & 7;    // channels 8*ql .. 8*ql+7
  int base = blockIdx.x * 32;
  int node = base + wv * 8 + q;
  if (node < n) {
    int e0 = rowStart[node];
    if ((node & 255) == 0) e0 = (node >> 8) * CAP;  // bucket start (rowStart[g] holds ends)
    int e1 = rowStart[node + 1];
    float di = dinv[node];
    uint4 su = H8[(size_t)node * 8 + ql];
    float a0 = di * bfLo(su.x), a1 = di * bfHi(su.x);
    float a2 = di * bfLo(su.y), a3 = di * bfHi(su.y);
    float a4 = di * bfLo(su.z), a5 = di * bfHi(su.z);
    float a6 = di * bfLo(su.w), a7 = di * bfHi(su.w);
    for (int b2 = e0 & ~1; b2 < e1; b2 += 8) {
      AGG_STEP8(edges, H8, ql, e0, e1, b2)
    }
    float4 bv0 = ((const float4*)bias)[2 * ql];
    float4 bv1 = ((const float4*)bias)[2 * ql + 1];
    a0 = fmaxf(a0 + bv0.x, 0.f); a1 = fmaxf(a1 + bv0.y, 0.f);
    a2 = fmaxf(a2 + bv0.z, 0.f); a3 = fmaxf(a3 + bv0.w, 0.f);
    a4 = fmaxf(a4 + bv1.x, 0.f); a5 = fmaxf(a5 + bv1.y, 0.f);
    a6 = fmaxf(a6 + bv1.z, 0.f); a7 = fmaxf(a7 + bv1.w, 0.f);
    uint4 o;
    o.x = (unsigned)f2bf(a0) | ((unsigned)f2bf(a1) << 16);
    o.y = (unsigned)f2bf(a2) | ((unsigned)f2bf(a3) << 16);
    o.z = (unsigned)f2bf(a4) | ((unsigned)f2bf(a5) << 16);
    o.w = (unsigned)f2bf(a6) | ((unsigned)f2bf(a7) << 16);
    sh[wv * 8 + q][ql] = o;
    if (ql == 0) sdi[wv * 8 + q] = di;
  } else {
    sh[wv * 8 + q][ql] = make_uint4(0, 0, 0, 0);
    if (ql == 0) sdi[wv * 8 + q] = 0.f;
  }
  __syncthreads();
  // ---- gemm2 phase: 32 rows from LDS; this wave owns n-tile nt = wv ----
  int m16 = lane & 15;
  int qq = lane >> 4;
  bf16x8 Bb[2], Br[2];
#pragma unroll
  for (int kh = 0; kh < 2; ++kh) {
    int ncol = wv * 16 + m16;
    int k0 = kh * 32 + qq * 8;
#pragma unroll
    for (int j = 0; j < 8; ++j) {
      float w = W[(k0 + j) * HID + ncol];  // L1-hot (16 KB)
      unsigned short wb = f2bf(w);
      Bb[kh][j] = (short)wb;
      Br[kh][j] = (short)f2bf(w - bf2f(wb));
    }
  }
#pragma unroll
  for (int rt = 0; rt < 2; ++rt) {
    int row = rt * 16 + m16;
    bf16x8 A0 = *(const bf16x8*)&sh[row][qq];      // k = qq*8 .. +7
    bf16x8 A1 = *(const bf16x8*)&sh[row][4 + qq];  // k = 32 + qq*8 .. +7
    f32x4 acc = {0.f, 0.f, 0.f, 0.f};
    acc = __builtin_amdgcn_mfma_f32_16x16x32_bf16(Bb[0], A0, acc, 0, 0, 0);
    acc = __builtin_amdgcn_mfma_f32_16x16x32_bf16(Bb[1], A1, acc, 0, 0, 0);
    acc = __builtin_amdgcn_mfma_f32_16x16x32_bf16(Br[0], A0, acc, 0, 0, 0);
    acc = __builtin_amdgcn_mfma_f32_16x16x32_bf16(Br[1], A1, acc, 0, 0, 0);
    int gnode = base + row;
    if (gnode < n) {
      float dv = sdi[row];
      ushort4 o;
      o.x = f2bf(acc[0] * dv);
      o.y = f2bf(acc[1] * dv);
      o.z = f2bf(acc[2] * dv);
      o.w = f2bf(acc[3] * dv);
      *(ushort4*)(&Out[(size_t)gnode * HID + wv * 16 + qq * 4]) = o;
    }
  }
}

// ---- CSR aggregate (layer 2): 8 nodes per wave, float4 output + bias ----
__global__ __launch_bounds__(256) void k_agg8f(const int2* __restrict__ edges,
                                               const int* __restrict__ rowStart,
                                               const float* __restrict__ dinv,
                                               const uint4* __restrict__ H8,  // P2
                                               const float* __restrict__ bias,
                                               float* __restrict__ outp, int n) {
  int gwave = (blockIdx.x * 256 + threadIdx.x) >> 6;
  int lane = threadIdx.x & 63;
  int q = lane >> 3;
  int ql = lane & 7;
  int node = gwave * 8 + q;
  if (node >= n) return;
  int e0 = rowStart[node];
  if ((node & 255) == 0) e0 = (node >> 8) * CAP;
  int e1 = rowStart[node + 1];
  float di = dinv[node];
  uint4 su = H8[(size_t)node * 8 + ql];
  float a0 = di * bfLo(su.x), a1 = di * bfHi(su.x);
  float a2 = di * bfLo(su.y), a3 = di * bfHi(su.y);
  float a4 = di * bfLo(su.z), a5 = di * bfHi(su.z);
  float a6 = di * bfLo(su.w), a7 = di * bfHi(su.w);
  for (int b2 = e0 & ~1; b2 < e1; b2 += 8) {
    AGG_STEP8(edges, H8, ql, e0, e1, b2)
  }
  float4 bv0 = ((const float4*)bias)[2 * ql];
  float4 bv1 = ((const float4*)bias)[2 * ql + 1];
  float4 o0, o1;
  o0.x = a0 + bv0.x; o0.y = a1 + bv0.y; o0.z = a2 + bv0.z; o0.w = a3 + bv0.w;
  o1.x = a4 + bv1.x; o1.y = a5 + bv1.y; o1.z = a6 + bv1.z; o1.w = a7 + bv1.w;
  ((float4*)outp)[(size_t)node * 16 + 2 * ql] = o0;
  ((float4*)outp)[(size_t)node * 16 + 2 * ql + 1] = o1;
}

extern "C" void kernel_launch(void* const* d_in, const int* in_sizes, int n_in,
                              void* d_out, int out_size, void* d_ws, size_t ws_size,
                              hipStream_t stream) {
  const float* x  = (const float*)d_in[0];
  const int*   ei = (const int*)d_in[1];
  const float* ew = (const float*)d_in[2];
  const float* W1 = (const float*)d_in[3];
  const float* b1 = (const float*)d_in[4];
  const float* W2 = (const float*)d_in[5];
  const float* b2 = (const float*)d_in[6];
  float* out = (float*)d_out;

  const int n  = in_sizes[0] / HID;   // 100000
  const int nE = in_sizes[2];         // 1000000
  const int* src = ei;
  const int* dst = ei + nE;

  const int B = (n + NPB - 1) / NPB;  // 391 buckets
  const int G1  = (nE + DFT * 4 - 1) / (DFT * 4);     // 489 blocks
  const int ept = (nE + G1 * DFT - 1) / (G1 * DFT);   // 4

  // ---- workspace layout (~23.2 MB) ----
  auto align512 = [](size_t v) { return (v + 511) & ~(size_t)511; };
  char* ws = (char*)d_ws;
  size_t off = 0;
  float* dinv        = (float*)(ws + off); off += align512((size_t)n * 4);
  int*   rowStart    = (int*)  (ws + off); off += align512((size_t)(n + 1) * 4);
  unsigned int* bucketCnt = (unsigned int*)(ws + off); off += align512((size_t)B * 16 * 4);
  int2*  edges       = (int2*) (ws + off); off += align512((size_t)B * CAP * 8 + 128);
  unsigned short* P2 = (unsigned short*)(ws + off); off += align512((size_t)n * HID * 2);
  // P1 (12.8 MB bf16) lives in d_out's first half: dead before k_agg8f
  // (the only writer of d_out) runs.
  unsigned short* P1 = (unsigned short*)d_out;

  const int aggBlocks = (n + 31) / 32;  // 32 nodes per block (4 waves x 8)

  // ---- 5 dispatches total ----
  hipMemsetAsync(bucketCnt, 0, (size_t)B * 16 * 4, stream);
  k_bucket1<<<G1, DFT, 0, stream>>>(src, dst, ew, bucketCnt, edges, B, ept, nE);
  k_degfillG<<<B, DFT, 0, stream>>>(edges, bucketCnt, x, W1, dinv, rowStart, P1, n);

  // layer-1 aggregate fused with layer-2 projection (P1 -> P2)
  k_aggG<<<aggBlocks, 256, 0, stream>>>(edges, rowStart, dinv,
                                        (const uint4*)P1, b1, W2, P2, n);

  // layer-2 aggregate -> final output
  k_agg8f<<<aggBlocks, 256, 0, stream>>>(edges, rowStart, dinv,
                                         (const uint4*)P2, b2, out, n);
}